// Round 4
// baseline (114.640 us; speedup 1.0000x reference)
//
#include <hip/hip_runtime.h>
#include <hip/hip_bf16.h>
#include <stdint.h>

#define B_    8
#define CIN   64
#define COUT  64
#define NPATH 9
#define H_    128
#define W_    128
#define HW    16384
#define PTOT  131072   // B*H*W
#define NBIN  72       // NPATH * B_
#define CHUNK 256      // pixels per k_conv block
#define NCHUNKS 584    // 131072/256 + 72 (worst-case padding)
#define MAXCHUNK 1024

typedef float  f32x4  __attribute__((ext_vector_type(4)));
typedef __bf16 bf16x8 __attribute__((ext_vector_type(8)));
typedef short  short8 __attribute__((ext_vector_type(8)));
typedef unsigned short ushort4v __attribute__((ext_vector_type(4)));

__device__ __forceinline__ short f2bf(float f) {
    __bf16 b = (__bf16)f;
    return __builtin_bit_cast(short, b);
}
__device__ __forceinline__ float bf2f(unsigned short u) {
    unsigned v = ((unsigned)u) << 16;
    return __builtin_bit_cast(float, v);
}

// ---------------------------------------------------------------- K0b:
// kernels_w (N,COUT,CIN,3,3) f32 -> WbF[n][s][f][lane][j] bf16 (MFMA fragment order)
// fragment (s,f): lane l holds A[row=f*16+(l&15)][k=s*32+(l>>4)*8+j]
__global__ void k_w_frag(const float* __restrict__ kw,
                         unsigned short* __restrict__ WbF) {
    int o = blockIdx.x * 256 + threadIdx.x;     // 331776 total
    int j    = o & 7;
    int lane = (o >> 3) & 63;
    int f    = (o >> 9) & 3;
    int rest = o >> 11;
    int s    = rest % 18;
    int n    = rest / 18;
    int c    = f * 16 + (lane & 15);
    int kg   = lane >> 4;
    int ci   = ((s & 1) << 5) + (kg << 3) + j;
    int tap  = s >> 1;
    WbF[o] = (unsigned short)f2bf(kw[((n * 64 + c) * 64 + ci) * 9 + tap]);
}

// ---------------------------------------------------------------- K1:
// fp32 observer scores + argmax + compaction; ALSO emits Xb bf16 NHWC
__global__ void k_scores_bin(const float* __restrict__ x,
                             const float* __restrict__ w1, const float* __restrict__ b1,
                             const float* __restrict__ w2, const float* __restrict__ b2,
                             unsigned* __restrict__ gcnt, unsigned* __restrict__ lists,
                             unsigned short* __restrict__ Xb) {
    __shared__ float sw1[2048];   // [32][64]
    __shared__ float sw2[288];    // [9][32]
    __shared__ float sb1[32];
    __shared__ float sb2[9];
    __shared__ unsigned scnt[NBIN];
    __shared__ unsigned sbase[NBIN];
    int t = threadIdx.x;
    #pragma unroll
    for (int i = 0; i < 8; ++i) sw1[t + i * 256] = w1[t + i * 256];
    for (int i = t; i < 288; i += 256) sw2[i] = w2[i];
    if (t < 32) sb1[t] = b1[t];
    if (t < 9)  sb2[t] = b2[t];
    if (t < NBIN) scnt[t] = 0u;
    __syncthreads();

    int p  = blockIdx.x * 256 + t;
    int b  = p >> 14;
    const float* xp = x + (size_t)b * 64 * HW + (p & 16383);
    float xv[64];
    #pragma unroll
    for (int ci = 0; ci < 64; ++ci) xv[ci] = xp[ci * HW];

    #pragma unroll
    for (int j = 0; j < 8; ++j) {
        short8 v;
        #pragma unroll
        for (int q = 0; q < 8; ++q) v[q] = f2bf(xv[j * 8 + q]);
        *(short8*)(Xb + (((size_t)p) << 6) + j * 8) = v;
    }

    float s[9];
    #pragma unroll
    for (int nn = 0; nn < 9; ++nn) s[nn] = sb2[nn];

    for (int j = 0; j < 32; ++j) {
        float a = sb1[j];
        const float4* wv = (const float4*)&sw1[j * 64];
        #pragma unroll
        for (int q = 0; q < 16; ++q) {
            float4 v = wv[q];
            a += xv[q*4+0]*v.x + xv[q*4+1]*v.y + xv[q*4+2]*v.z + xv[q*4+3]*v.w;
        }
        float hsig = tanhf(a);
        #pragma unroll
        for (int nn = 0; nn < 9; ++nn) s[nn] += hsig * sw2[nn * 32 + j];
    }
    float best = s[0]; int bi = 0;
    #pragma unroll
    for (int nn = 1; nn < 9; ++nn) if (s[nn] > best) { best = s[nn]; bi = nn; }

    int bin = bi * 8 + b;
    unsigned rank = atomicAdd(&scnt[bin], 1u);
    __syncthreads();
    if (t < NBIN && scnt[t]) sbase[t] = atomicAdd(&gcnt[t], scnt[t]);
    __syncthreads();
    lists[bin * 16384 + sbase[bin] + rank] = (unsigned)p;
}

// ---------------------------------------------------------------- K1b:
// prefix sum over bins (CHUNK-aligned) + chunk->bin table
__global__ void k_prefix(const unsigned* __restrict__ gcnt, unsigned* __restrict__ binstart,
                         unsigned* __restrict__ chunktab) {
    __shared__ unsigned st[NBIN + 1];
    int t = threadIdx.x;
    for (int i = t; i < MAXCHUNK; i += 256) chunktab[i] = 0xFFFFFFFFu;
    if (t == 0) {
        unsigned acc = 0;
        for (int bin = 0; bin < NBIN; ++bin) {
            st[bin] = acc;
            acc += ((gcnt[bin] + (CHUNK - 1u)) / CHUNK) * CHUNK;
        }
        st[NBIN] = acc;
    }
    __syncthreads();
    if (t <= NBIN) binstart[t] = st[t];
    if (t < NBIN) {
        unsigned c0 = st[t] / CHUNK, c1 = st[t + 1] / CHUNK;
        for (unsigned k = c0; k < c1; ++k) chunktab[k] = (unsigned)t;
    }
}

// ---------------------------------------------------------------- K2:
// gathered implicit-GEMM selected conv.
// 512 thr = 8 waves; wave: 2 groups x 16 px, all 64 out ch.
// Weights staged async (global_load_lds) in fragment order (conflict-free ds_read).
// ALL 36 B-gathers issued up front into registers (branch-free via zero-row).
// Yc stored bf16; fused IN stats.
__global__ __launch_bounds__(512, 2) void k_conv(
        const unsigned short* __restrict__ Xb, const unsigned short* __restrict__ WbF,
        const float* __restrict__ kb, const unsigned* __restrict__ gcnt,
        const unsigned* __restrict__ binstart, const unsigned* __restrict__ chunktab,
        const unsigned* __restrict__ lists, const unsigned short* __restrict__ zrow,
        unsigned short* __restrict__ Yc, float* __restrict__ sums) {
    __shared__ char wlds[73728];              // [s][f][lane][16B], exact, no pad
    __shared__ float lsum[64], lsq[64];
    int t = threadIdx.x;
    unsigned bin = chunktab[blockIdx.x];
    if (bin == 0xFFFFFFFFu) return;
    int n = bin >> 3;
    int b = bin & 7;
    int wid = t >> 6, lane = t & 63, kg = lane >> 4, l15 = lane & 15;

    // ---- async weight staging: 72 x 1KB chunks, 9 per wave
    {
        const unsigned short* src = WbF + n * 36864;
        #pragma unroll
        for (int k = 0; k < 9; ++k) {
            int i = wid * 9 + k;
            __builtin_amdgcn_global_load_lds(
                (const __attribute__((address_space(1))) unsigned int*)(src + i * 512 + lane * 8),
                (__attribute__((address_space(3))) unsigned int*)(&wlds[i * 1024]),
                16, 0, 0);
        }
    }
    if (t < 64) { lsum[t] = 0.f; lsq[t] = 0.f; }

    unsigned cnt = gcnt[bin];
    int local_base = (int)(blockIdx.x * (unsigned)CHUNK - binstart[bin]);

    int hh[2], ww[2], val[2];
    const unsigned short* xr[2];
    size_t yb[2];
    #pragma unroll
    for (int g = 0; g < 2; ++g) {
        int pidx = local_base + wid * 32 + g * 16 + l15;
        val[g] = pidx < (int)cnt;
        int pcl = val[g] ? pidx : (int)cnt - 1;
        unsigned p = lists[bin * 16384 + pcl];
        hh[g] = (p >> 7) & 127;
        ww[g] = p & 127;
        xr[g] = Xb + (((size_t)p) << 6);
        yb[g] = ((size_t)p) << 6;
    }

    // ---- issue ALL 36 gathers (branch-free; OOB -> zero row)
    short8 w0[18], w1[18];
    #pragma unroll
    for (int s = 0; s < 18; ++s) {
        const int tap = s >> 1;
        const int dh = tap / 3 - 1, dw = tap % 3 - 1;
        const int koff = ((s & 1) << 5) + (kg << 3);        // shorts
        {
            int h2 = hh[0] + dh, w2 = ww[0] + dw;
            const unsigned short* bp = ((unsigned)h2 < 128u && (unsigned)w2 < 128u)
                ? xr[0] + ((dh * 128 + dw) << 6) : zrow;
            w0[s] = *(const short8*)(bp + koff);
        }
        {
            int h2 = hh[1] + dh, w2 = ww[1] + dw;
            const unsigned short* bp = ((unsigned)h2 < 128u && (unsigned)w2 < 128u)
                ? xr[1] + ((dh * 128 + dw) << 6) : zrow;
            w1[s] = *(const short8*)(bp + koff);
        }
    }
    asm volatile("" ::: "memory");   // keep all loads issued before the barrier
    __syncthreads();                 // drains staging + gathers (vmcnt 0)

    f32x4 acc[2][4];
    #pragma unroll
    for (int g = 0; g < 2; ++g)
        #pragma unroll
        for (int f = 0; f < 4; ++f) acc[g][f] = (f32x4)0.0f;

    #pragma unroll
    for (int s = 0; s < 18; ++s) {
        bf16x8 b0 = __builtin_bit_cast(bf16x8, w0[s]);
        bf16x8 b1 = __builtin_bit_cast(bf16x8, w1[s]);
        #pragma unroll
        for (int f = 0; f < 4; ++f) {
            short8 araw = *(const short8*)(&wlds[((s * 4 + f) * 64 + lane) * 16]);
            bf16x8 af = __builtin_bit_cast(bf16x8, araw);
            acc[0][f] = __builtin_amdgcn_mfma_f32_16x16x32_bf16(af, b0, acc[0][f], 0, 0, 0);
            acc[1][f] = __builtin_amdgcn_mfma_f32_16x16x32_bf16(af, b1, acc[1][f], 0, 0, 0);
        }
    }

    // ---- epilogue: bias + relu + bf16 Yc store + stats
    float s1[16], s2[16];
    #pragma unroll
    for (int i = 0; i < 16; ++i) { s1[i] = 0.f; s2[i] = 0.f; }
    #pragma unroll
    for (int g = 0; g < 2; ++g) {
        #pragma unroll
        for (int f = 0; f < 4; ++f) {
            f32x4 bias = *(const f32x4*)(kb + n * 64 + f * 16 + kg * 4);
            f32x4 v;
            #pragma unroll
            for (int r = 0; r < 4; ++r) v[r] = fmaxf(acc[g][f][r] + bias[r], 0.0f);
            if (val[g]) {
                ushort4v o;
                #pragma unroll
                for (int r = 0; r < 4; ++r) o[r] = (unsigned short)f2bf(v[r]);
                *(ushort4v*)(Yc + yb[g] + f * 16 + kg * 4) = o;
            }
            #pragma unroll
            for (int r = 0; r < 4; ++r) {
                float sv = val[g] ? v[r] : 0.0f;
                s1[f * 4 + r] += sv;
                s2[f * 4 + r] += sv * sv;
            }
        }
    }
    #pragma unroll
    for (int m = 1; m < 16; m <<= 1) {
        #pragma unroll
        for (int i = 0; i < 16; ++i) {
            s1[i] += __shfl_xor(s1[i], m, 64);
            s2[i] += __shfl_xor(s2[i], m, 64);
        }
    }
    if (l15 == 0) {
        #pragma unroll
        for (int i = 0; i < 16; ++i) {
            int c = (i >> 2) * 16 + (kg << 2) + (i & 3);
            atomicAdd(&lsum[c], s1[i]);
            atomicAdd(&lsq[c],  s2[i]);
        }
    }
    __syncthreads();
    if (t < 64) {
        atomicAdd(&sums[b * 64 + t],       lsum[t]);
        atomicAdd(&sums[512 + b * 64 + t], lsq[t]);
    }
}

// ---------------------------------------------------------------- K3:
// contiguous bf16 Yc rows -> LDS transpose -> normalized coalesced NCHW f32 store
__global__ void k_final(const unsigned short* __restrict__ Yc, const float* __restrict__ sums,
                        const float* __restrict__ gamma, const float* __restrict__ beta,
                        float* __restrict__ out) {
    __shared__ float ld[128][66];
    __shared__ float smu[64], srs[64], sg[64], sb[64];
    int t = threadIdx.x;
    int b = blockIdx.y, hw0 = blockIdx.x * 128;
    if (t < 64) {
        float mu = sums[b * 64 + t] * (1.0f / HW);
        float vr = sums[512 + b * 64 + t] * (1.0f / HW) - mu * mu;
        smu[t] = mu;
        srs[t] = rsqrtf(fmaxf(vr, 0.0f) + 1e-5f);
        sg[t] = gamma[t]; sb[t] = beta[t];
    }
    int i = t >> 1, half = t & 1;
    const short8* row = (const short8*)(Yc + (((size_t)(b * HW + hw0 + i)) << 6) + half * 32);
    #pragma unroll
    for (int q = 0; q < 4; ++q) {
        short8 v = row[q];
        #pragma unroll
        for (int j = 0; j < 8; ++j)
            ld[i][half * 32 + q * 8 + j] = bf2f((unsigned short)v[j]);
    }
    __syncthreads();
    #pragma unroll
    for (int rep = 0; rep < 32; ++rep) {
        int idx = rep * 256 + t;          // 8192 = 64c x 128hw
        int c = idx >> 7, j = idx & 127;
        float v = (ld[j][c] - smu[c]) * srs[c] * sg[c] + sb[c];
        out[(((size_t)b * 64 + c) << 14) + hw0 + j] = v;
    }
}

extern "C" void kernel_launch(void* const* d_in, const int* in_sizes, int n_in,
                              void* d_out, int out_size, void* d_ws, size_t ws_size,
                              hipStream_t stream) {
    const float* x    = (const float*)d_in[0];
    const float* kw   = (const float*)d_in[1];
    const float* kb   = (const float*)d_in[2];
    const float* w1   = (const float*)d_in[3];
    const float* b1   = (const float*)d_in[4];
    const float* w2   = (const float*)d_in[5];
    const float* b2   = (const float*)d_in[6];
    const float* gam  = (const float*)d_in[7];
    const float* bet  = (const float*)d_in[8];
    float* out = (float*)d_out;

    char* ws = (char*)d_ws;
    unsigned* gcnt      = (unsigned*)(ws + 0);          // 72 u32
    unsigned* binstart  = (unsigned*)(ws + 512);        // 73 u32
    unsigned* chunktab  = (unsigned*)(ws + 1024);       // 1024 u32
    float*    sums      = (float*)   (ws + 8192);       // 1024 f32
    unsigned short* zrow = (unsigned short*)(ws + 12288); // 128 B zeros
    unsigned* lists     = (unsigned*)(ws + 16384);      // 72*16384 u32 (4.72 MB)
    unsigned short* Yc  = (unsigned short*)(ws + 5242880);  // 16.78 MB bf16
    unsigned short* Xb  = (unsigned short*)(ws + 22020096); // 16.78 MB bf16
    unsigned short* WbF = (unsigned short*)(ws + 38797312); // 0.66 MB
    // total ws usage ~39.5 MB

    hipMemsetAsync(gcnt, 0, 512, stream);
    hipMemsetAsync(ws + 8192, 0, 4352, stream);   // sums + zrow
    k_w_frag<<<1296, 256, 0, stream>>>(kw, WbF);
    k_scores_bin<<<512, 256, 0, stream>>>(x, w1, b1, w2, b2, gcnt, lists, Xb);
    k_prefix<<<1, 256, 0, stream>>>(gcnt, binstart, chunktab);
    k_conv<<<NCHUNKS, 512, 0, stream>>>(Xb, WbF, kb, gcnt, binstart, chunktab, lists,
                                        zrow, Yc, sums);
    k_final<<<dim3(128, 8), 256, 0, stream>>>(Yc, sums, gam, bet, out);
}

// Round 5
// 109.774 us; speedup vs baseline: 1.0443x; 1.0443x over previous
//
#include <hip/hip_runtime.h>
#include <hip/hip_bf16.h>
#include <stdint.h>

#define B_    8
#define CIN   64
#define COUT  64
#define NPATH 9
#define H_    128
#define W_    128
#define HW    16384
#define PTOT  131072   // B*H*W
#define NBIN  72       // NPATH * B_
#define CHUNK 128      // pixels per k_conv block (8 waves x 16 px)
#define NCHUNKS 1096   // 131072/128 + 72 (worst-case bin padding)

typedef float  f32x4  __attribute__((ext_vector_type(4)));
typedef __bf16 bf16x8 __attribute__((ext_vector_type(8)));
typedef short  short8 __attribute__((ext_vector_type(8)));
typedef unsigned short ushort4v __attribute__((ext_vector_type(4)));

__device__ __forceinline__ short f2bf(float f) {
    __bf16 b = (__bf16)f;
    return __builtin_bit_cast(short, b);
}
__device__ __forceinline__ float bf2f(unsigned short u) {
    unsigned v = ((unsigned)u) << 16;
    return __builtin_bit_cast(float, v);
}

// ---------------------------------------------------------------- K1 (fused):
// blocks 0..511:  fp32 observer scores + argmax + compaction + Xb bf16 NHWC emit
// blocks 512..592: kernels_w (N,COUT,CIN,3,3) f32 -> WbF MFMA-fragment order
//   fragment (s,f): lane l holds A[row=f*16+(l&15)][k=s*32+(l>>4)*8+j]
__global__ void k_pre(const float* __restrict__ x,
                      const float* __restrict__ w1, const float* __restrict__ b1,
                      const float* __restrict__ w2, const float* __restrict__ b2,
                      const float* __restrict__ kw,
                      unsigned* __restrict__ gcnt, unsigned* __restrict__ lists,
                      unsigned short* __restrict__ Xb,
                      unsigned short* __restrict__ WbF) {
    int t = threadIdx.x;
    if (blockIdx.x >= 512) {
        // ---- weight fragment transform: 81 blocks x 256 thr x 16 elems
        int ob = ((int)blockIdx.x - 512) * 4096 + t * 16;
        #pragma unroll
        for (int j = 0; j < 16; ++j) {
            int o = ob + j;
            int jj   = o & 7;
            int lane = (o >> 3) & 63;
            int f    = (o >> 9) & 3;
            int rest = o >> 11;
            int s    = rest % 18;
            int n    = rest / 18;
            int c    = f * 16 + (lane & 15);
            int kg   = lane >> 4;
            int ci   = ((s & 1) << 5) + (kg << 3) + jj;
            int tap  = s >> 1;
            WbF[o] = (unsigned short)f2bf(kw[((n * 64 + c) * 64 + ci) * 9 + tap]);
        }
        return;
    }
    __shared__ float sw1[2048];   // [32][64]
    __shared__ float sw2[288];    // [9][32]
    __shared__ float sb1[32];
    __shared__ float sb2[9];
    __shared__ unsigned scnt[NBIN];
    __shared__ unsigned sbase[NBIN];
    #pragma unroll
    for (int i = 0; i < 8; ++i) sw1[t + i * 256] = w1[t + i * 256];
    for (int i = t; i < 288; i += 256) sw2[i] = w2[i];
    if (t < 32) sb1[t] = b1[t];
    if (t < 9)  sb2[t] = b2[t];
    if (t < NBIN) scnt[t] = 0u;
    __syncthreads();

    int p  = blockIdx.x * 256 + t;
    int b  = p >> 14;
    const float* xp = x + (size_t)b * 64 * HW + (p & 16383);
    float xv[64];
    #pragma unroll
    for (int ci = 0; ci < 64; ++ci) xv[ci] = xp[ci * HW];

    #pragma unroll
    for (int j = 0; j < 8; ++j) {
        short8 v;
        #pragma unroll
        for (int q = 0; q < 8; ++q) v[q] = f2bf(xv[j * 8 + q]);
        *(short8*)(Xb + (((size_t)p) << 6) + j * 8) = v;
    }

    float s[9];
    #pragma unroll
    for (int nn = 0; nn < 9; ++nn) s[nn] = sb2[nn];

    for (int j = 0; j < 32; ++j) {
        float a = sb1[j];
        const float4* wv = (const float4*)&sw1[j * 64];
        #pragma unroll
        for (int q = 0; q < 16; ++q) {
            float4 v = wv[q];
            a += xv[q*4+0]*v.x + xv[q*4+1]*v.y + xv[q*4+2]*v.z + xv[q*4+3]*v.w;
        }
        float hsig = tanhf(a);
        #pragma unroll
        for (int nn = 0; nn < 9; ++nn) s[nn] += hsig * sw2[nn * 32 + j];
    }
    float best = s[0]; int bi = 0;
    #pragma unroll
    for (int nn = 1; nn < 9; ++nn) if (s[nn] > best) { best = s[nn]; bi = nn; }

    int bin = bi * 8 + b;
    unsigned rank = atomicAdd(&scnt[bin], 1u);
    __syncthreads();
    if (t < NBIN && scnt[t]) sbase[t] = atomicAdd(&gcnt[t], scnt[t]);
    __syncthreads();
    lists[bin * 16384 + sbase[bin] + rank] = (unsigned)p;
}

// ---------------------------------------------------------------- K2:
// gathered implicit-GEMM selected conv.
// 512 thr = 8 waves; wave: 16 px, all 64 out ch. Per-block bin scan (no k_prefix).
// Weights async-staged (global_load_lds) in fragment order; all 18 B-gathers
// in flight per wave (clamped addresses, validity mask applied post-barrier).
__global__ __launch_bounds__(512, 4) void k_conv(
        const unsigned short* __restrict__ Xb, const unsigned short* __restrict__ WbF,
        const float* __restrict__ kb, const unsigned* __restrict__ gcnt,
        const unsigned* __restrict__ lists,
        unsigned short* __restrict__ Yc, float* __restrict__ sums) {
    __shared__ char wlds[73728];              // [s][f][lane][16B], exact, no pad
    __shared__ float lsum[64], lsq[64];
    __shared__ unsigned sg[NBIN];
    __shared__ int sinfo[3];                  // bin, local_base, cnt
    int t = threadIdx.x;
    if (t < NBIN) sg[t] = gcnt[t];
    if (t < 64) { lsum[t] = 0.f; lsq[t] = 0.f; }
    __syncthreads();
    if (t == 0) {
        unsigned acc = 0, target = blockIdx.x * (unsigned)CHUNK;
        int bf = -1; unsigned bs = 0, bc = 0;
        for (int bin = 0; bin < NBIN; ++bin) {
            unsigned c = sg[bin];
            unsigned al = (c + (CHUNK - 1u)) & ~(CHUNK - 1u);
            if (target >= acc && target < acc + al) { bf = bin; bs = target - acc; bc = c; }
            acc += al;
        }
        sinfo[0] = bf; sinfo[1] = (int)bs; sinfo[2] = (int)bc;
    }
    __syncthreads();
    int bin = sinfo[0];
    if (bin < 0) return;
    int n = bin >> 3, b = bin & 7;
    int wid = t >> 6, lane = t & 63, kg = lane >> 4, l15 = lane & 15;

    // ---- async weight staging: 72 x 1KB chunks, 9 per wave
    {
        const unsigned short* src = WbF + n * 36864;
        #pragma unroll
        for (int k = 0; k < 9; ++k) {
            int i = wid * 9 + k;
            __builtin_amdgcn_global_load_lds(
                (const __attribute__((address_space(1))) unsigned int*)(src + i * 512 + lane * 8),
                (__attribute__((address_space(3))) unsigned int*)(&wlds[i * 1024]),
                16, 0, 0);
        }
    }

    int cnt = sinfo[2];
    int pidx = sinfo[1] + wid * 16 + l15;
    int valid = pidx < cnt;
    unsigned p = lists[bin * 16384 + (valid ? pidx : cnt - 1)];
    int hw0 = (int)(p & 16383);
    int hh = hw0 >> 7, ww = hw0 & 127;
    const unsigned short* xr = Xb + (((size_t)p) << 6);
    const int koff = (kg << 3);

    // ---- issue ALL 18 gathers (clamped addresses; validity mask for later)
    short8 w[18];
    unsigned inbm = 0;
    #pragma unroll
    for (int s = 0; s < 18; ++s) {
        const int tap = s >> 1;
        const int dh = tap / 3 - 1, dw = tap % 3 - 1;
        int h2 = hh + dh, w2 = ww + dw;
        if ((unsigned)h2 < 128u && (unsigned)w2 < 128u) inbm |= (1u << s);
        int h2c = min(max(h2, 0), 127), w2c = min(max(w2, 0), 127);
        int off = (((h2c << 7) + w2c - hw0) << 6) + ((s & 1) << 5) + koff;
        w[s] = *(const short8*)(xr + off);
    }
    __syncthreads();                 // staging (and loads) drained

    f32x4 acc[4];
    #pragma unroll
    for (int f = 0; f < 4; ++f) acc[f] = (f32x4)0.0f;
    const short8 zero8 = (short8)0;

    #pragma unroll
    for (int s = 0; s < 18; ++s) {
        short8 raw = ((inbm >> s) & 1u) ? w[s] : zero8;
        bf16x8 bb = __builtin_bit_cast(bf16x8, raw);
        #pragma unroll
        for (int f = 0; f < 4; ++f) {
            short8 araw = *(const short8*)(&wlds[((s * 4 + f) * 64 + lane) * 16]);
            bf16x8 af = __builtin_bit_cast(bf16x8, araw);
            acc[f] = __builtin_amdgcn_mfma_f32_16x16x32_bf16(af, bb, acc[f], 0, 0, 0);
        }
    }

    // ---- epilogue: bias + relu + bf16 Yc store + IN stats
    size_t yb = ((size_t)p) << 6;
    float s1[16], s2[16];
    #pragma unroll
    for (int f = 0; f < 4; ++f) {
        f32x4 bias = *(const f32x4*)(kb + n * 64 + f * 16 + kg * 4);
        f32x4 v;
        #pragma unroll
        for (int r = 0; r < 4; ++r) v[r] = fmaxf(acc[f][r] + bias[r], 0.0f);
        if (valid) {
            ushort4v o;
            #pragma unroll
            for (int r = 0; r < 4; ++r) o[r] = (unsigned short)f2bf(v[r]);
            *(ushort4v*)(Yc + yb + f * 16 + kg * 4) = o;
        }
        #pragma unroll
        for (int r = 0; r < 4; ++r) {
            float sv = valid ? v[r] : 0.0f;
            s1[f * 4 + r] = sv;
            s2[f * 4 + r] = sv * sv;
        }
    }
    #pragma unroll
    for (int m = 1; m < 16; m <<= 1) {
        #pragma unroll
        for (int i = 0; i < 16; ++i) {
            s1[i] += __shfl_xor(s1[i], m, 64);
            s2[i] += __shfl_xor(s2[i], m, 64);
        }
    }
    if (l15 == 0) {
        #pragma unroll
        for (int i = 0; i < 16; ++i) {
            int c = (i >> 2) * 16 + (kg << 2) + (i & 3);
            atomicAdd(&lsum[c], s1[i]);
            atomicAdd(&lsq[c],  s2[i]);
        }
    }
    __syncthreads();
    if (t < 64) {
        atomicAdd(&sums[b * 64 + t],       lsum[t]);
        atomicAdd(&sums[512 + b * 64 + t], lsq[t]);
    }
}

// ---------------------------------------------------------------- K3:
// contiguous bf16 Yc rows -> LDS transpose -> normalized coalesced NCHW f32 store
__global__ void k_final(const unsigned short* __restrict__ Yc, const float* __restrict__ sums,
                        const float* __restrict__ gamma, const float* __restrict__ beta,
                        float* __restrict__ out) {
    __shared__ float ld[128][66];
    __shared__ float smu[64], srs[64], sg[64], sb[64];
    int t = threadIdx.x;
    int b = blockIdx.y, hw0 = blockIdx.x * 128;
    if (t < 64) {
        float mu = sums[b * 64 + t] * (1.0f / HW);
        float vr = sums[512 + b * 64 + t] * (1.0f / HW) - mu * mu;
        smu[t] = mu;
        srs[t] = rsqrtf(fmaxf(vr, 0.0f) + 1e-5f);
        sg[t] = gamma[t]; sb[t] = beta[t];
    }
    int i = t >> 1, half = t & 1;
    const short8* row = (const short8*)(Yc + (((size_t)(b * HW + hw0 + i)) << 6) + half * 32);
    #pragma unroll
    for (int q = 0; q < 4; ++q) {
        short8 v = row[q];
        #pragma unroll
        for (int j = 0; j < 8; ++j)
            ld[i][half * 32 + q * 8 + j] = bf2f((unsigned short)v[j]);
    }
    __syncthreads();
    #pragma unroll
    for (int rep = 0; rep < 32; ++rep) {
        int idx = rep * 256 + t;          // 8192 = 64c x 128hw
        int c = idx >> 7, j = idx & 127;
        float v = (ld[j][c] - smu[c]) * srs[c] * sg[c] + sb[c];
        out[(((size_t)b * 64 + c) << 14) + hw0 + j] = v;
    }
}

extern "C" void kernel_launch(void* const* d_in, const int* in_sizes, int n_in,
                              void* d_out, int out_size, void* d_ws, size_t ws_size,
                              hipStream_t stream) {
    const float* x    = (const float*)d_in[0];
    const float* kw   = (const float*)d_in[1];
    const float* kb   = (const float*)d_in[2];
    const float* w1   = (const float*)d_in[3];
    const float* b1   = (const float*)d_in[4];
    const float* w2   = (const float*)d_in[5];
    const float* b2   = (const float*)d_in[6];
    const float* gam  = (const float*)d_in[7];
    const float* bet  = (const float*)d_in[8];
    float* out = (float*)d_out;

    char* ws = (char*)d_ws;
    unsigned* gcnt      = (unsigned*)(ws + 0);          // 72 u32
    float*    sums      = (float*)   (ws + 4096);       // 1024 f32
    unsigned* lists     = (unsigned*)(ws + 16384);      // 72*16384 u32 (4.72 MB)
    unsigned short* Yc  = (unsigned short*)(ws + 5242880);  // 16.78 MB bf16
    unsigned short* Xb  = (unsigned short*)(ws + 22020096); // 16.78 MB bf16
    unsigned short* WbF = (unsigned short*)(ws + 38797312); // 0.66 MB
    // total ws usage ~39.5 MB

    hipMemsetAsync(ws, 0, 8192, stream);    // gcnt + sums
    k_pre<<<593, 256, 0, stream>>>(x, w1, b1, w2, b2, kw, gcnt, lists, Xb, WbF);
    k_conv<<<NCHUNKS, 512, 0, stream>>>(Xb, WbF, kb, gcnt, lists, Yc, sums);
    k_final<<<dim3(128, 8), 256, 0, stream>>>(Yc, sums, gam, bet, out);
}

// Round 6
// 109.771 us; speedup vs baseline: 1.0444x; 1.0000x over previous
//
#include <hip/hip_runtime.h>
#include <hip/hip_bf16.h>
#include <stdint.h>

#define B_    8
#define CIN   64
#define COUT  64
#define NPATH 9
#define H_    128
#define W_    128
#define HW    16384
#define PTOT  131072   // B*H*W
#define NBIN  72       // NPATH * B_
#define CHUNK 64       // pixels per k_conv block (8 waves, 64 px, all 64 ch)
#define NCHUNKS 2120   // 131072/64 + 72 (worst-case bin padding)
#define MAXCHUNK 4096

typedef float  f32x4  __attribute__((ext_vector_type(4)));
typedef __bf16 bf16x8 __attribute__((ext_vector_type(8)));
typedef short  short8 __attribute__((ext_vector_type(8)));
typedef unsigned short ushort4v __attribute__((ext_vector_type(4)));

__device__ __forceinline__ short f2bf(float f) {
    __bf16 b = (__bf16)f;
    return __builtin_bit_cast(short, b);
}
__device__ __forceinline__ float bf2f(unsigned short u) {
    unsigned v = ((unsigned)u) << 16;
    return __builtin_bit_cast(float, v);
}

// ---------------------------------------------------------------- K1 (fused):
// blocks 0..511:  fp32 observer scores + argmax + compaction + Xb bf16 NHWC emit
// blocks 512..592: kernels_w (N,COUT,CIN,3,3) f32 -> WbF MFMA-fragment order
//   fragment (s,f): lane l holds A[row=f*16+(l&15)][k=s*32+(l>>4)*8+j]
__global__ void k_pre(const float* __restrict__ x,
                      const float* __restrict__ w1, const float* __restrict__ b1,
                      const float* __restrict__ w2, const float* __restrict__ b2,
                      const float* __restrict__ kw,
                      unsigned* __restrict__ gcnt, unsigned* __restrict__ lists,
                      unsigned short* __restrict__ Xb,
                      unsigned short* __restrict__ WbF) {
    int t = threadIdx.x;
    if (blockIdx.x >= 512) {
        int ob = ((int)blockIdx.x - 512) * 4096 + t * 16;
        #pragma unroll
        for (int j = 0; j < 16; ++j) {
            int o = ob + j;
            int jj   = o & 7;
            int lane = (o >> 3) & 63;
            int f    = (o >> 9) & 3;
            int rest = o >> 11;
            int s    = rest % 18;
            int n    = rest / 18;
            int c    = f * 16 + (lane & 15);
            int kg   = lane >> 4;
            int ci   = ((s & 1) << 5) + (kg << 3) + jj;
            int tap  = s >> 1;
            WbF[o] = (unsigned short)f2bf(kw[((n * 64 + c) * 64 + ci) * 9 + tap]);
        }
        return;
    }
    __shared__ float sw1[2048];   // [32][64]
    __shared__ float sw2[288];    // [9][32]
    __shared__ float sb1[32];
    __shared__ float sb2[9];
    __shared__ unsigned scnt[NBIN];
    __shared__ unsigned sbase[NBIN];
    #pragma unroll
    for (int i = 0; i < 8; ++i) sw1[t + i * 256] = w1[t + i * 256];
    for (int i = t; i < 288; i += 256) sw2[i] = w2[i];
    if (t < 32) sb1[t] = b1[t];
    if (t < 9)  sb2[t] = b2[t];
    if (t < NBIN) scnt[t] = 0u;
    __syncthreads();

    int p  = blockIdx.x * 256 + t;
    int b  = p >> 14;
    const float* xp = x + (size_t)b * 64 * HW + (p & 16383);
    float xv[64];
    #pragma unroll
    for (int ci = 0; ci < 64; ++ci) xv[ci] = xp[ci * HW];

    #pragma unroll
    for (int j = 0; j < 8; ++j) {
        short8 v;
        #pragma unroll
        for (int q = 0; q < 8; ++q) v[q] = f2bf(xv[j * 8 + q]);
        *(short8*)(Xb + (((size_t)p) << 6) + j * 8) = v;
    }

    float s[9];
    #pragma unroll
    for (int nn = 0; nn < 9; ++nn) s[nn] = sb2[nn];

    for (int j = 0; j < 32; ++j) {
        float a = sb1[j];
        const float4* wv = (const float4*)&sw1[j * 64];
        #pragma unroll
        for (int q = 0; q < 16; ++q) {
            float4 v = wv[q];
            a += xv[q*4+0]*v.x + xv[q*4+1]*v.y + xv[q*4+2]*v.z + xv[q*4+3]*v.w;
        }
        float hsig = tanhf(a);
        #pragma unroll
        for (int nn = 0; nn < 9; ++nn) s[nn] += hsig * sw2[nn * 32 + j];
    }
    float best = s[0]; int bi = 0;
    #pragma unroll
    for (int nn = 1; nn < 9; ++nn) if (s[nn] > best) { best = s[nn]; bi = nn; }

    int bin = bi * 8 + b;
    unsigned rank = atomicAdd(&scnt[bin], 1u);
    __syncthreads();
    if (t < NBIN && scnt[t]) sbase[t] = atomicAdd(&gcnt[t], scnt[t]);
    __syncthreads();
    lists[bin * 16384 + sbase[bin] + rank] = (unsigned)p;
}

// ---------------------------------------------------------------- K1b:
// per-chunk info table: bin(8b)<<32 | cnt(16b)<<16 | local_base(16b)
__global__ void k_prefix(const unsigned* __restrict__ gcnt,
                         unsigned long long* __restrict__ chunkinfo) {
    __shared__ unsigned st[NBIN + 1];
    int t = threadIdx.x;
    for (int i = t; i < MAXCHUNK; i += 256) chunkinfo[i] = ~0ull;
    if (t == 0) {
        unsigned acc = 0;
        for (int bin = 0; bin < NBIN; ++bin) {
            st[bin] = acc;
            acc += (gcnt[bin] + (CHUNK - 1u)) / CHUNK;
        }
        st[NBIN] = acc;
    }
    __syncthreads();
    if (t < NBIN) {
        unsigned c0 = st[t], c1 = st[t + 1], cnt = gcnt[t];
        for (unsigned k = c0; k < c1; ++k)
            chunkinfo[k] = ((unsigned long long)t << 32)
                         | ((unsigned long long)cnt << 16)
                         | (unsigned long long)((k - c0) * CHUNK);
    }
}

// ---------------------------------------------------------------- K2:
// gathered implicit-GEMM selected conv, ALL operands staged via global_load_lds.
// 512 thr = 8 waves; block: 64 px of one (path,batch) bin, all 64 out ch.
// Wlds: 72 fragments x 64 lanes x 16B (72 KB).
// Blds: [tap][px][8 x 16B parts], part-index XOR-swizzled by (px&7) (72 KB).
// Wave: f = wid&3, pixel-groups {2*(wid>>2), +1}; 36 MFMA/wave.
__global__ __launch_bounds__(512, 2) void k_conv(
        const unsigned short* __restrict__ Xb, const unsigned short* __restrict__ WbF,
        const float* __restrict__ kb, const unsigned* __restrict__ lists,
        const unsigned long long* __restrict__ chunkinfo,
        unsigned short* __restrict__ Yc, float* __restrict__ sums) {
    __shared__ char wlds[73728];
    __shared__ char blds[73728];
    __shared__ float lsum[64], lsq[64];
    int t = threadIdx.x;
    if (t < 64) { lsum[t] = 0.f; lsq[t] = 0.f; }
    unsigned long long info = chunkinfo[blockIdx.x];
    if (info == ~0ull) return;
    int bin  = (int)(info >> 32);
    int cnt  = (int)((info >> 16) & 0xFFFFu);
    int base = (int)(info & 0xFFFFu);
    int n = bin >> 3, b = bin & 7;
    int wid = t >> 6, lane = t & 63, kg = lane >> 4, l15 = lane & 15;

    // ---- stage weights: 4608 x 16B chunks, linear
    {
        const unsigned short* src = WbF + n * 36864;
        #pragma unroll
        for (int k = 0; k < 9; ++k) {
            int c = k * 512 + t;
            __builtin_amdgcn_global_load_lds(
                (const __attribute__((address_space(1))) unsigned int*)(src + c * 8),
                (__attribute__((address_space(3))) unsigned int*)(&wlds[c * 16]),
                16, 0, 0);
        }
    }
    // ---- stage gathered B: thread t owns (px = t>>3, part q = t&7), 9 taps
    {
        int px = t >> 3, q = t & 7;
        int pos = base + px;
        int posc = min(pos, cnt - 1);
        unsigned p = lists[bin * 16384 + posc];
        int h = (int)((p >> 7) & 127u), w = (int)(p & 127u);
        unsigned pb = p & ~16383u;
        int qs = (q ^ (px & 7)) * 8;              // swizzled source part (shorts)
        #pragma unroll
        for (int k = 0; k < 9; ++k) {
            int dh = k / 3 - 1, dw = k % 3 - 1;
            int h2 = min(max(h + dh, 0), 127);
            int w2 = min(max(w + dw, 0), 127);
            const unsigned short* src = Xb + ((size_t)(pb | (unsigned)((h2 << 7) + w2)) << 6) + qs;
            __builtin_amdgcn_global_load_lds(
                (const __attribute__((address_space(1))) unsigned int*)src,
                (__attribute__((address_space(3))) unsigned int*)(&blds[k * 8192 + t * 16]),
                16, 0, 0);
        }
    }
    __syncthreads();     // drains all staging (vmcnt 0)

    int f = wid & 3, gh = wid >> 2;
    // per-group pixel info for masks + epilogue
    unsigned pg[2]; int vg[2], inbm[2];
    #pragma unroll
    for (int gi = 0; gi < 2; ++gi) {
        int px = (gh * 2 + gi) * 16 + l15;
        int pos = base + px;
        vg[gi] = pos < cnt;
        pg[gi] = lists[bin * 16384 + min(pos, cnt - 1)];
        int h = (int)((pg[gi] >> 7) & 127u), w = (int)(pg[gi] & 127u);
        int m = 0;
        #pragma unroll
        for (int tap = 0; tap < 9; ++tap) {
            int dh = tap / 3 - 1, dw = tap % 3 - 1;
            if ((unsigned)(h + dh) < 128u && (unsigned)(w + dw) < 128u) m |= (1 << tap);
        }
        inbm[gi] = vg[gi] ? m : 0;
    }

    f32x4 acc[2];
    acc[0] = (f32x4)0.0f; acc[1] = (f32x4)0.0f;
    const short8 zero8 = (short8)0;

    #pragma unroll
    for (int s = 0; s < 18; ++s) {
        const int tap = s >> 1, half = s & 1;
        short8 araw = *(const short8*)(&wlds[((s * 4 + f) * 64 + lane) * 16]);
        bf16x8 af = __builtin_bit_cast(bf16x8, araw);
        const int q = ((half << 2) + kg) ^ (l15 & 7);
        #pragma unroll
        for (int gi = 0; gi < 2; ++gi) {
            int px = (gh * 2 + gi) * 16 + l15;
            short8 braw = *(const short8*)(&blds[tap * 8192 + px * 128 + q * 16]);
            short8 sel = ((inbm[gi] >> tap) & 1) ? braw : zero8;
            bf16x8 bb = __builtin_bit_cast(bf16x8, sel);
            acc[gi] = __builtin_amdgcn_mfma_f32_16x16x32_bf16(af, bb, acc[gi], 0, 0, 0);
        }
    }

    // ---- epilogue: bias + relu + bf16 Yc store + IN stats
    f32x4 bias = *(const f32x4*)(kb + n * 64 + f * 16 + kg * 4);
    float s1[4] = {0.f, 0.f, 0.f, 0.f}, s2[4] = {0.f, 0.f, 0.f, 0.f};
    #pragma unroll
    for (int gi = 0; gi < 2; ++gi) {
        f32x4 v;
        #pragma unroll
        for (int r = 0; r < 4; ++r) v[r] = fmaxf(acc[gi][r] + bias[r], 0.0f);
        if (vg[gi]) {
            ushort4v o;
            #pragma unroll
            for (int r = 0; r < 4; ++r) o[r] = (unsigned short)f2bf(v[r]);
            *(ushort4v*)(Yc + (((size_t)pg[gi]) << 6) + f * 16 + kg * 4) = o;
        }
        #pragma unroll
        for (int r = 0; r < 4; ++r) {
            float sv = vg[gi] ? v[r] : 0.0f;
            s1[r] += sv;
            s2[r] += sv * sv;
        }
    }
    #pragma unroll
    for (int m = 1; m < 16; m <<= 1) {
        #pragma unroll
        for (int r = 0; r < 4; ++r) {
            s1[r] += __shfl_xor(s1[r], m, 64);
            s2[r] += __shfl_xor(s2[r], m, 64);
        }
    }
    if (l15 == 0) {
        #pragma unroll
        for (int r = 0; r < 4; ++r) {
            int c = f * 16 + kg * 4 + r;
            atomicAdd(&lsum[c], s1[r]);
            atomicAdd(&lsq[c],  s2[r]);
        }
    }
    __syncthreads();
    if (t < 64) {
        atomicAdd(&sums[b * 64 + t],       lsum[t]);
        atomicAdd(&sums[512 + b * 64 + t], lsq[t]);
    }
}

// ---------------------------------------------------------------- K3:
// contiguous bf16 Yc rows -> LDS transpose -> normalized coalesced NCHW f32 store
__global__ void k_final(const unsigned short* __restrict__ Yc, const float* __restrict__ sums,
                        const float* __restrict__ gamma, const float* __restrict__ beta,
                        float* __restrict__ out) {
    __shared__ float ld[128][66];
    __shared__ float smu[64], srs[64], sg[64], sb[64];
    int t = threadIdx.x;
    int b = blockIdx.y, hw0 = blockIdx.x * 128;
    if (t < 64) {
        float mu = sums[b * 64 + t] * (1.0f / HW);
        float vr = sums[512 + b * 64 + t] * (1.0f / HW) - mu * mu;
        smu[t] = mu;
        srs[t] = rsqrtf(fmaxf(vr, 0.0f) + 1e-5f);
        sg[t] = gamma[t]; sb[t] = beta[t];
    }
    int i = t >> 1, half = t & 1;
    const short8* row = (const short8*)(Yc + (((size_t)(b * HW + hw0 + i)) << 6) + half * 32);
    #pragma unroll
    for (int q = 0; q < 4; ++q) {
        short8 v = row[q];
        #pragma unroll
        for (int j = 0; j < 8; ++j)
            ld[i][half * 32 + q * 8 + j] = bf2f((unsigned short)v[j]);
    }
    __syncthreads();
    #pragma unroll
    for (int rep = 0; rep < 32; ++rep) {
        int idx = rep * 256 + t;          // 8192 = 64c x 128hw
        int c = idx >> 7, j = idx & 127;
        float v = (ld[j][c] - smu[c]) * srs[c] * sg[c] + sb[c];
        out[(((size_t)b * 64 + c) << 14) + hw0 + j] = v;
    }
}

extern "C" void kernel_launch(void* const* d_in, const int* in_sizes, int n_in,
                              void* d_out, int out_size, void* d_ws, size_t ws_size,
                              hipStream_t stream) {
    const float* x    = (const float*)d_in[0];
    const float* kw   = (const float*)d_in[1];
    const float* kb   = (const float*)d_in[2];
    const float* w1   = (const float*)d_in[3];
    const float* b1   = (const float*)d_in[4];
    const float* w2   = (const float*)d_in[5];
    const float* b2   = (const float*)d_in[6];
    const float* gam  = (const float*)d_in[7];
    const float* bet  = (const float*)d_in[8];
    float* out = (float*)d_out;

    char* ws = (char*)d_ws;
    unsigned* gcnt      = (unsigned*)(ws + 0);            // 72 u32
    float*    sums      = (float*)   (ws + 4096);         // 1024 f32
    unsigned long long* chunkinfo = (unsigned long long*)(ws + 16384); // 4096 u64
    unsigned* lists     = (unsigned*)(ws + 65536);        // 72*16384 u32 (4.72 MB)
    unsigned short* Yc  = (unsigned short*)(ws + 5308416);   // 16.78 MB bf16
    unsigned short* Xb  = (unsigned short*)(ws + 22085632);  // 16.78 MB bf16
    unsigned short* WbF = (unsigned short*)(ws + 38862848);  // 0.66 MB
    // total ws usage ~39.6 MB

    hipMemsetAsync(ws, 0, 8192, stream);    // gcnt + sums
    k_pre<<<593, 256, 0, stream>>>(x, w1, b1, w2, b2, kw, gcnt, lists, Xb, WbF);
    k_prefix<<<1, 256, 0, stream>>>(gcnt, chunkinfo);
    k_conv<<<NCHUNKS, 512, 0, stream>>>(Xb, WbF, kb, lists, chunkinfo, Yc, sums);
    k_final<<<dim3(128, 8), 256, 0, stream>>>(Yc, sums, gam, bet, out);
}

// Round 7
// 98.099 us; speedup vs baseline: 1.1686x; 1.1190x over previous
//
#include <hip/hip_runtime.h>
#include <hip/hip_bf16.h>
#include <stdint.h>

#define B_    8
#define CIN   64
#define COUT  64
#define NPATH 9
#define H_    128
#define W_    128
#define HW    16384
#define PTOT  131072   // B*H*W
#define NBIN  72       // NPATH * B_
#define CHUNK 64       // pixels per chunk
#define NBLK  256      // persistent k_conv blocks (1 per CU)

typedef float  f32x4  __attribute__((ext_vector_type(4)));
typedef __bf16 bf16x8 __attribute__((ext_vector_type(8)));
typedef short  short8 __attribute__((ext_vector_type(8)));
typedef unsigned short ushort4v __attribute__((ext_vector_type(4)));

__device__ __forceinline__ short f2bf(float f) {
    __bf16 b = (__bf16)f;
    return __builtin_bit_cast(short, b);
}
__device__ __forceinline__ float bf2f(unsigned short u) {
    unsigned v = ((unsigned)u) << 16;
    return __builtin_bit_cast(float, v);
}

// ---------------------------------------------------------------- K1 (fused):
// blocks 0..511:  fp32 observer scores + argmax + compaction + Xb bf16 NHWC emit
// blocks 512..592: kernels_w (N,COUT,CIN,3,3) f32 -> WbF MFMA-fragment order
//   WbF[n][s][f][lane][j]: lane l holds A[row=f*16+(l&15)][k=s*32+(l>>4)*8+j]
__global__ void k_pre(const float* __restrict__ x,
                      const float* __restrict__ w1, const float* __restrict__ b1,
                      const float* __restrict__ w2, const float* __restrict__ b2,
                      const float* __restrict__ kw,
                      unsigned* __restrict__ gcnt, unsigned* __restrict__ lists,
                      unsigned short* __restrict__ Xb,
                      unsigned short* __restrict__ WbF) {
    int t = threadIdx.x;
    if (blockIdx.x >= 512) {
        int ob = ((int)blockIdx.x - 512) * 4096 + t * 16;
        #pragma unroll
        for (int j = 0; j < 16; ++j) {
            int o = ob + j;
            int jj   = o & 7;
            int lane = (o >> 3) & 63;
            int f    = (o >> 9) & 3;
            int rest = o >> 11;
            int s    = rest % 18;
            int n    = rest / 18;
            int c    = f * 16 + (lane & 15);
            int kg   = lane >> 4;
            int ci   = ((s & 1) << 5) + (kg << 3) + jj;
            int tap  = s >> 1;
            WbF[o] = (unsigned short)f2bf(kw[((n * 64 + c) * 64 + ci) * 9 + tap]);
        }
        return;
    }
    __shared__ float sw1[2048];   // [32][64]
    __shared__ float sw2[288];    // [9][32]
    __shared__ float sb1[32];
    __shared__ float sb2[9];
    __shared__ unsigned scnt[NBIN];
    __shared__ unsigned sbase[NBIN];
    #pragma unroll
    for (int i = 0; i < 8; ++i) sw1[t + i * 256] = w1[t + i * 256];
    for (int i = t; i < 288; i += 256) sw2[i] = w2[i];
    if (t < 32) sb1[t] = b1[t];
    if (t < 9)  sb2[t] = b2[t];
    if (t < NBIN) scnt[t] = 0u;
    __syncthreads();

    int p  = blockIdx.x * 256 + t;
    int b  = p >> 14;
    const float* xp = x + (size_t)b * 64 * HW + (p & 16383);
    float xv[64];
    #pragma unroll
    for (int ci = 0; ci < 64; ++ci) xv[ci] = xp[ci * HW];

    #pragma unroll
    for (int j = 0; j < 8; ++j) {
        short8 v;
        #pragma unroll
        for (int q = 0; q < 8; ++q) v[q] = f2bf(xv[j * 8 + q]);
        *(short8*)(Xb + (((size_t)p) << 6) + j * 8) = v;
    }

    float s[9];
    #pragma unroll
    for (int nn = 0; nn < 9; ++nn) s[nn] = sb2[nn];

    for (int j = 0; j < 32; ++j) {
        float a = sb1[j];
        const float4* wv = (const float4*)&sw1[j * 64];
        #pragma unroll
        for (int q = 0; q < 16; ++q) {
            float4 v = wv[q];
            a += xv[q*4+0]*v.x + xv[q*4+1]*v.y + xv[q*4+2]*v.z + xv[q*4+3]*v.w;
        }
        float hsig = tanhf(a);
        #pragma unroll
        for (int nn = 0; nn < 9; ++nn) s[nn] += hsig * sw2[nn * 32 + j];
    }
    float best = s[0]; int bi = 0;
    #pragma unroll
    for (int nn = 1; nn < 9; ++nn) if (s[nn] > best) { best = s[nn]; bi = nn; }

    int bin = bi * 8 + b;
    unsigned rank = atomicAdd(&scnt[bin], 1u);
    __syncthreads();
    if (t < NBIN && scnt[t]) sbase[t] = atomicAdd(&gcnt[t], scnt[t]);
    __syncthreads();
    lists[bin * 16384 + sbase[bin] + rank] = (unsigned)p;
}

// ---------------------------------------------------------------- K1b:
// chunkinfo[k] = bin<<32 | cnt<<16 | local_base; ctot = total chunk count
__global__ void k_prefix(const unsigned* __restrict__ gcnt,
                         unsigned long long* __restrict__ chunkinfo,
                         unsigned* __restrict__ ctot) {
    __shared__ unsigned st[NBIN + 1];
    int t = threadIdx.x;
    if (t == 0) {
        unsigned acc = 0;
        for (int bin = 0; bin < NBIN; ++bin) {
            st[bin] = acc;
            acc += (gcnt[bin] + (CHUNK - 1u)) / CHUNK;
        }
        st[NBIN] = acc;
        *ctot = acc;
    }
    __syncthreads();
    if (t < NBIN) {
        unsigned c0 = st[t], cnt = gcnt[t];
        unsigned nch = (cnt + (CHUNK - 1u)) / CHUNK;
        for (unsigned k = 0; k < nch; ++k)
            chunkinfo[c0 + k] = ((unsigned long long)t << 32)
                              | ((unsigned long long)cnt << 16)
                              | (unsigned long long)(k * CHUNK);
    }
}

// ---------------------------------------------------------------- K2:
// persistent gathered implicit-GEMM selected conv (counted-vmcnt double buffer).
// 256 blocks x 512 thr (8 waves). Each block: contiguous chunk range of ~C/256.
// Weights in REGISTERS (18 frags/wave, reloaded on rare bin switch).
// B neighborhood double-buffered in LDS (2 x 72 KB) via global_load_lds,
// part-index XOR-swizzled. Never drain vmcnt to 0 in steady state.
__global__ __launch_bounds__(512, 2) void k_conv(
        const unsigned short* __restrict__ Xb, const unsigned short* __restrict__ WbF,
        const float* __restrict__ kb, const unsigned* __restrict__ lists,
        const unsigned long long* __restrict__ chunkinfo, const unsigned* __restrict__ ctot,
        unsigned short* __restrict__ Yc, float* __restrict__ sums) {
    __shared__ char blds[2][73728];
    int t = threadIdx.x;
    int wid = t >> 6, lane = t & 63, kg = lane >> 4, l15 = lane & 15;
    int f = wid & 3, gh = wid >> 2;
    int spx = t >> 3;                       // staging pixel 0..63
    int sq8 = ((t & 7) ^ (spx & 7)) * 8;    // swizzled source part (shorts)

    unsigned C = *ctot;
    unsigned bid = (blockIdx.x & 7) * 32 + (blockIdx.x >> 3);  // XCD-chunked swizzle
    unsigned c0 = (bid * C) / NBLK, c1 = ((bid + 1) * C) / NBLK;
    if (c0 >= c1) return;

    #define STAGE9(P, BUF) do {                                                   \
        unsigned p_ = (P);                                                        \
        int h_ = (int)((p_ >> 7) & 127u), w_ = (int)(p_ & 127u);                  \
        unsigned pb_ = p_ & ~16383u;                                              \
        _Pragma("unroll")                                                         \
        for (int k_ = 0; k_ < 9; ++k_) {                                          \
            int dh_ = k_ / 3 - 1, dw_ = k_ % 3 - 1;                               \
            int h2_ = min(max(h_ + dh_, 0), 127);                                 \
            int w2_ = min(max(w_ + dw_, 0), 127);                                 \
            const unsigned short* src_ =                                          \
                Xb + ((size_t)(pb_ | (unsigned)((h2_ << 7) + w2_)) << 6) + sq8;   \
            __builtin_amdgcn_global_load_lds(                                     \
                (const __attribute__((address_space(1))) unsigned int*)src_,      \
                (__attribute__((address_space(3))) unsigned int*)((BUF) + k_ * 8192 + t * 16), \
                16, 0, 0);                                                        \
        }                                                                         \
    } while (0)

    // ---- prologue: chunk c0 metadata + weights + stage into buf 0
    unsigned long long info = chunkinfo[c0];
    int bin  = (int)(info >> 32);
    int cnt  = (int)((info >> 16) & 0xFFFFu);
    int base = (int)(info & 0xFFFFu);
    int n = bin >> 3, b = bin & 7;

    short8 wv[18];
    #pragma unroll
    for (int s = 0; s < 18; ++s)
        wv[s] = *(const short8*)(WbF + n * 36864 + ((s * 4 + f) * 64 + lane) * 8);
    f32x4 bias = *(const f32x4*)(kb + n * 64 + f * 16 + kg * 4);

    unsigned pc0 = lists[bin * 16384 + min(base + gh * 32 + l15,      cnt - 1)];
    unsigned pc1 = lists[bin * 16384 + min(base + gh * 32 + 16 + l15, cnt - 1)];
    { unsigned ps = lists[bin * 16384 + min(base + spx, cnt - 1)];
      STAGE9(ps, blds[0]); }

    int cur = 0;
    float s1[4] = {0.f,0.f,0.f,0.f}, s2[4] = {0.f,0.f,0.f,0.f};

    for (unsigned c = c0; c < c1; ++c) {
        bool last = (c + 1 >= c1);
        int bin_n = bin, cnt_n = cnt, base_n = base;
        unsigned pn0 = 0, pn1 = 0;
        if (!last) {
            unsigned long long in2 = chunkinfo[c + 1];
            bin_n  = (int)(in2 >> 32);
            cnt_n  = (int)((in2 >> 16) & 0xFFFFu);
            base_n = (int)(in2 & 0xFFFFu);
            pn0 = lists[bin_n * 16384 + min(base_n + gh * 32 + l15,      cnt_n - 1)];
            pn1 = lists[bin_n * 16384 + min(base_n + gh * 32 + 16 + l15, cnt_n - 1)];
            { unsigned ps = lists[bin_n * 16384 + min(base_n + spx, cnt_n - 1)];
              STAGE9(ps, blds[cur ^ 1]); }
            asm volatile("s_waitcnt vmcnt(11)" ::: "memory");   // chunk c staged; 9+2 in flight
        } else {
            asm volatile("s_waitcnt vmcnt(0)" ::: "memory");
        }
        __builtin_amdgcn_sched_barrier(0);
        __builtin_amdgcn_s_barrier();

        // ---- masks for current chunk
        int v0 = (base + gh * 32 + l15)      < cnt ? 1 : 0;
        int v1 = (base + gh * 32 + 16 + l15) < cnt ? 1 : 0;
        int inb0 = 0, inb1 = 0;
        {
            int h0 = (int)((pc0 >> 7) & 127u), w0 = (int)(pc0 & 127u);
            int h1 = (int)((pc1 >> 7) & 127u), w1 = (int)(pc1 & 127u);
            #pragma unroll
            for (int tap = 0; tap < 9; ++tap) {
                int dh = tap / 3 - 1, dw = tap % 3 - 1;
                if ((unsigned)(h0 + dh) < 128u && (unsigned)(w0 + dw) < 128u) inb0 |= (1 << tap);
                if ((unsigned)(h1 + dh) < 128u && (unsigned)(w1 + dw) < 128u) inb1 |= (1 << tap);
            }
            inb0 = v0 ? inb0 : 0;
            inb1 = v1 ? inb1 : 0;
        }

        // ---- MFMA phase (A from regs, B from LDS)
        f32x4 acc0 = (f32x4)0.0f, acc1 = (f32x4)0.0f;
        const short8 zero8 = (short8)0;
        const char* bufc = blds[cur];
        #pragma unroll
        for (int s = 0; s < 18; ++s) {
            const int tap = s >> 1, half = s & 1;
            bf16x8 af = __builtin_bit_cast(bf16x8, wv[s]);
            const int q = (((half << 2) + kg) ^ (l15 & 7)) * 16;
            {
                int px = gh * 32 + l15;
                short8 braw = *(const short8*)(bufc + tap * 8192 + px * 128 + q);
                short8 sel = ((inb0 >> tap) & 1) ? braw : zero8;
                acc0 = __builtin_amdgcn_mfma_f32_16x16x32_bf16(
                           af, __builtin_bit_cast(bf16x8, sel), acc0, 0, 0, 0);
            }
            {
                int px = gh * 32 + 16 + l15;
                short8 braw = *(const short8*)(bufc + tap * 8192 + px * 128 + q);
                short8 sel = ((inb1 >> tap) & 1) ? braw : zero8;
                acc1 = __builtin_amdgcn_mfma_f32_16x16x32_bf16(
                           af, __builtin_bit_cast(bf16x8, sel), acc1, 0, 0, 0);
            }
        }

        // ---- epilogue: bias + relu + bf16 store + local stats
        {
            f32x4 o0, o1;
            #pragma unroll
            for (int r = 0; r < 4; ++r) {
                o0[r] = fmaxf(acc0[r] + bias[r], 0.0f);
                o1[r] = fmaxf(acc1[r] + bias[r], 0.0f);
            }
            if (v0) {
                ushort4v u;
                #pragma unroll
                for (int r = 0; r < 4; ++r) u[r] = (unsigned short)f2bf(o0[r]);
                *(ushort4v*)(Yc + (((size_t)pc0) << 6) + f * 16 + kg * 4) = u;
            }
            if (v1) {
                ushort4v u;
                #pragma unroll
                for (int r = 0; r < 4; ++r) u[r] = (unsigned short)f2bf(o1[r]);
                *(ushort4v*)(Yc + (((size_t)pc1) << 6) + f * 16 + kg * 4) = u;
            }
            #pragma unroll
            for (int r = 0; r < 4; ++r) {
                float a = v0 ? o0[r] : 0.0f, bb = v1 ? o1[r] : 0.0f;
                s1[r] += a + bb;
                s2[r] += a * a + bb * bb;
            }
        }

        // ---- bin switch: flush stats, reload weights/bias
        if (!last && bin_n != bin) {
            float f1[4], f2[4];
            #pragma unroll
            for (int r = 0; r < 4; ++r) { f1[r] = s1[r]; f2[r] = s2[r]; s1[r] = 0.f; s2[r] = 0.f; }
            #pragma unroll
            for (int m = 1; m < 16; m <<= 1) {
                #pragma unroll
                for (int r = 0; r < 4; ++r) {
                    f1[r] += __shfl_xor(f1[r], m, 64);
                    f2[r] += __shfl_xor(f2[r], m, 64);
                }
            }
            if (l15 == 0) {
                #pragma unroll
                for (int r = 0; r < 4; ++r) {
                    int ch = f * 16 + kg * 4 + r;
                    atomicAdd(&sums[b * 64 + ch],       f1[r]);
                    atomicAdd(&sums[512 + b * 64 + ch], f2[r]);
                }
            }
            n = bin_n >> 3; b = bin_n & 7;
            #pragma unroll
            for (int s = 0; s < 18; ++s)
                wv[s] = *(const short8*)(WbF + n * 36864 + ((s * 4 + f) * 64 + lane) * 8);
            bias = *(const f32x4*)(kb + n * 64 + f * 16 + kg * 4);
        }
        bin = bin_n; cnt = cnt_n; base = base_n; pc0 = pn0; pc1 = pn1;
        cur ^= 1;
        __builtin_amdgcn_s_barrier();     // reads of old buf done before next overwrite
    }

    // ---- final stats flush
    #pragma unroll
    for (int m = 1; m < 16; m <<= 1) {
        #pragma unroll
        for (int r = 0; r < 4; ++r) {
            s1[r] += __shfl_xor(s1[r], m, 64);
            s2[r] += __shfl_xor(s2[r], m, 64);
        }
    }
    if (l15 == 0) {
        #pragma unroll
        for (int r = 0; r < 4; ++r) {
            int ch = f * 16 + kg * 4 + r;
            atomicAdd(&sums[b * 64 + ch],       s1[r]);
            atomicAdd(&sums[512 + b * 64 + ch], s2[r]);
        }
    }
    #undef STAGE9
}

// ---------------------------------------------------------------- K3:
// contiguous bf16 Yc rows -> LDS transpose -> normalized coalesced NCHW f32 store
__global__ void k_final(const unsigned short* __restrict__ Yc, const float* __restrict__ sums,
                        const float* __restrict__ gamma, const float* __restrict__ beta,
                        float* __restrict__ out) {
    __shared__ float ld[128][66];
    __shared__ float smu[64], srs[64], sg[64], sb[64];
    int t = threadIdx.x;
    int b = blockIdx.y, hw0 = blockIdx.x * 128;
    if (t < 64) {
        float mu = sums[b * 64 + t] * (1.0f / HW);
        float vr = sums[512 + b * 64 + t] * (1.0f / HW) - mu * mu;
        smu[t] = mu;
        srs[t] = rsqrtf(fmaxf(vr, 0.0f) + 1e-5f);
        sg[t] = gamma[t]; sb[t] = beta[t];
    }
    int i = t >> 1, half = t & 1;
    const short8* row = (const short8*)(Yc + (((size_t)(b * HW + hw0 + i)) << 6) + half * 32);
    #pragma unroll
    for (int q = 0; q < 4; ++q) {
        short8 v = row[q];
        #pragma unroll
        for (int j = 0; j < 8; ++j)
            ld[i][half * 32 + q * 8 + j] = bf2f((unsigned short)v[j]);
    }
    __syncthreads();
    #pragma unroll
    for (int rep = 0; rep < 32; ++rep) {
        int idx = rep * 256 + t;          // 8192 = 64c x 128hw
        int c = idx >> 7, j = idx & 127;
        float v = (ld[j][c] - smu[c]) * srs[c] * sg[c] + sb[c];
        out[(((size_t)b * 64 + c) << 14) + hw0 + j] = v;
    }
}

extern "C" void kernel_launch(void* const* d_in, const int* in_sizes, int n_in,
                              void* d_out, int out_size, void* d_ws, size_t ws_size,
                              hipStream_t stream) {
    const float* x    = (const float*)d_in[0];
    const float* kw   = (const float*)d_in[1];
    const float* kb   = (const float*)d_in[2];
    const float* w1   = (const float*)d_in[3];
    const float* b1   = (const float*)d_in[4];
    const float* w2   = (const float*)d_in[5];
    const float* b2   = (const float*)d_in[6];
    const float* gam  = (const float*)d_in[7];
    const float* bet  = (const float*)d_in[8];
    float* out = (float*)d_out;

    char* ws = (char*)d_ws;
    unsigned* gcnt      = (unsigned*)(ws + 0);            // 72 u32
    unsigned* ctot      = (unsigned*)(ws + 512);          // 1 u32
    float*    sums      = (float*)   (ws + 4096);         // 1024 f32
    unsigned long long* chunkinfo = (unsigned long long*)(ws + 16384); // up to 2120 u64
    unsigned* lists     = (unsigned*)(ws + 65536);        // 72*16384 u32 (4.72 MB)
    unsigned short* Yc  = (unsigned short*)(ws + 5308416);   // 16.78 MB bf16
    unsigned short* Xb  = (unsigned short*)(ws + 22085632);  // 16.78 MB bf16
    unsigned short* WbF = (unsigned short*)(ws + 38862848);  // 0.66 MB
    // total ws usage ~39.6 MB

    hipMemsetAsync(ws, 0, 8192, stream);    // gcnt + ctot + sums
    k_pre<<<593, 256, 0, stream>>>(x, w1, b1, w2, b2, kw, gcnt, lists, Xb, WbF);
    k_prefix<<<1, 256, 0, stream>>>(gcnt, chunkinfo, ctot);
    k_conv<<<NBLK, 512, 0, stream>>>(Xb, WbF, kb, lists, chunkinfo, ctot, Yc, sums);
    k_final<<<dim3(128, 8), 256, 0, stream>>>(Yc, sums, gam, bet, out);
}